// Round 2
// 306.670 us; speedup vs baseline: 1.0017x; 1.0017x over previous
//
#include <hip/hip_runtime.h>

// StationLoss: B=16, H=W=2048, S=5000, KERNEL_SIZE=3, METRIC=MSE
// Latency-bound scattered gather -> maximize memory-level parallelism:
//   4 lanes per station (one 3-wide window ROW per lane, lane 3 idle),
//   320k threads / 1250 blocks (~19.5 waves/CU vs 4.9 before).
//   Row partials combined with 2x shfl_xor inside the 4-lane group.
// Kernel 2 reduces the 1250 block partials to the scalar mean.

#define BB 16
#define HH 2048
#define WW 2048
#define SS 5000
#define NSTATIONS (BB * SS)            // 80000
#define LPS 4                          // lanes per station (3 active + 1 idle)
#define NTHREADS_TOTAL (NSTATIONS * LPS)  // 320000
#define THREADS 256
#define NBLOCKS (NTHREADS_TOTAL / THREADS)  // 1250 exactly

__global__ __launch_bounds__(THREADS) void station_partial_kernel(
    const float* __restrict__ pred,       // (B,1,H,W)
    const int2*  __restrict__ pos,        // (B,S,2) -> {px, py}
    const float* __restrict__ runoff,     // (B,S)
    float* __restrict__ partials)         // (NBLOCKS,)
{
    int t = blockIdx.x * blockDim.x + threadIdx.x;
    int s = t >> 2;                       // station index [0, NSTATIONS)
    int r = t & 3;                        // window row 0..2, r==3 idle

    float sum = 0.0f;
    float cnt = 0.0f;
    if (r < 3) {
        int b = s / SS;
        int2 p = pos[s];                  // p.x = px (width), p.y = py (height)
        int px = p.x;
        int py = p.y;

        int y = py + (r - 1);
        bool yok = (y >= 0) & (y < HH);
        int yc = min(max(y, 0), HH - 1);
        const float* row = pred + (size_t)b * (size_t)(HH * WW) + (size_t)yc * WW;

        #pragma unroll
        for (int dx = -1; dx <= 1; ++dx) {
            int x = px + dx;
            bool ok = yok & (x >= 0) & (x < WW);
            int xc = min(max(x, 0), WW - 1);
            float v = row[xc];            // clamped -> always in-bounds
            float m = ok ? 1.0f : 0.0f;
            sum += v * m;
            cnt += m;
        }
    }

    // combine the 3 row-partials within each 4-lane group (xor 1, xor 2)
    sum += __shfl_xor(sum, 1, 64);
    sum += __shfl_xor(sum, 2, 64);
    cnt += __shfl_xor(cnt, 1, 64);
    cnt += __shfl_xor(cnt, 2, 64);

    float contrib = 0.0f;
    if (r == 0) {
        float avg = sum / cnt;            // cnt >= 4 always
        float d = avg - runoff[s];        // runoff gathered by 1 lane per station
        contrib = d * d;
    }

    // wave-64 reduction (non-r0 lanes contribute 0)
    #pragma unroll
    for (int off = 32; off > 0; off >>= 1)
        contrib += __shfl_down(contrib, off, 64);

    __shared__ float waves[THREADS / 64];
    int lane = threadIdx.x & 63;
    int wid  = threadIdx.x >> 6;
    if (lane == 0) waves[wid] = contrib;
    __syncthreads();
    if (threadIdx.x == 0) {
        float blk = 0.0f;
        #pragma unroll
        for (int i = 0; i < THREADS / 64; ++i) blk += waves[i];
        partials[blockIdx.x] = blk;
    }
}

__global__ __launch_bounds__(512) void reduce_kernel(
    const float* __restrict__ partials, float* __restrict__ out)
{
    float v = 0.0f;
    for (int i = threadIdx.x; i < NBLOCKS; i += 512) v += partials[i];
    #pragma unroll
    for (int off = 32; off > 0; off >>= 1)
        v += __shfl_down(v, off, 64);

    __shared__ float waves[512 / 64];
    int lane = threadIdx.x & 63;
    int wid  = threadIdx.x >> 6;
    if (lane == 0) waves[wid] = v;
    __syncthreads();
    if (threadIdx.x == 0) {
        float s = 0.0f;
        #pragma unroll
        for (int i = 0; i < 512 / 64; ++i) s += waves[i];
        out[0] = s * (1.0f / (float)NSTATIONS);
    }
}

extern "C" void kernel_launch(void* const* d_in, const int* in_sizes, int n_in,
                              void* d_out, int out_size, void* d_ws, size_t ws_size,
                              hipStream_t stream) {
    const float* pred   = (const float*)d_in[0];
    const int2*  pos    = (const int2*)d_in[1];
    const float* runoff = (const float*)d_in[2];
    float* out      = (float*)d_out;
    float* partials = (float*)d_ws;

    station_partial_kernel<<<NBLOCKS, THREADS, 0, stream>>>(pred, pos, runoff, partials);
    reduce_kernel<<<1, 512, 0, stream>>>(partials, out);
}